// Round 14
// baseline (498.067 us; speedup 1.0000x reference)
//
#include <hip/hip_runtime.h>
#include <hip/hip_bf16.h>
#include <math.h>

// B=4096 queries, D=256, K=65536 centroids (f32).
// Round 13 (this session): scan block-TLP bet. r9-vs-r10 showed per-kt-step cost
// ~constant (2645 vs 2963 cyc) regardless of 2x work inside -> fixed serialized
// latency chain per step. Reg-capped ILP can't hide it; 2 independent blocks/CU
// can (one block's latency under the other's MFMA). Scan -> 512-thr blocks,
// grid (8,64): chalf=blockIdx.y&1 owns 256c/ct; As0 64K + pmred 4K = 68K/block,
// 2x68=136<=160 LDS; regs 56 arch (r10-measured, same loop) + 64 acc = 120 <=
// 128 -> __launch_bounds__(512,4) pins 4 waves/SIMD (r1's spill was 232>128;
// this fits). pm -> [16][4096] rows kc*2+chalf; grp = kc*256+ct*16+chalf*8+w.
// Also: cmax fused into splitc (ctl zeroed via hipMemsetAsync), 5->4 launches.
// Predict: scan 95-125us + MfmaUtil 50-65% if TLP hides latency; unchanged 158
// -> scan plateau declared. Revert: FETCH>200MB / scan>165 / absmax!=0.
// Round 14: byte-identical resubmission -- r13 bench died to infra (container
// failed twice), hypothesis still untested.

#define DDIM 256
#define QTILE 128
#define STSZ 8192      // centroids per kc strip (16 ct x 512c; block covers 256c/ct)
#define QCAP 48        // candidate groups per query
#define F16_MINN 6.103515625e-5f

typedef __attribute__((ext_vector_type(8))) _Float16 half8;
typedef __attribute__((ext_vector_type(4))) _Float16 half4;
typedef __attribute__((ext_vector_type(4))) float f32x4;

__device__ __forceinline__ void gl_lds16(const void* g, void* l) {
  __builtin_amdgcn_global_load_lds((const __attribute__((address_space(1))) void*)g,
                                   (__attribute__((address_space(3))) void*)l, 16, 0, 0);
}

// exact order-preserving float -> uint key (finite floats; matches f32 <)
__device__ __forceinline__ unsigned fkey(float d) {
  unsigned ud = __float_as_uint(d);
  return ud ^ (((int)ud < 0) ? 0xFFFFFFFFu : 0x80000000u);
}

// ---------------- centroid split + c_sq + cmax fused (wave = one 256-elem row) -----
__global__ __launch_bounds__(256) void splitc_kernel(const float* __restrict__ in,
                                                     _Float16* __restrict__ o0,
                                                     float* __restrict__ c_sq,
                                                     unsigned* __restrict__ ctl) {
  __shared__ float red[4];
  int i = blockIdx.x * 256 + threadIdx.x;   // 4-elem chunk id; wave = one row
  int lane = (int)threadIdx.x & 63, w = (int)threadIdx.x >> 6;
  float4 v = ((const float4*)in)[i];
  float vv[4] = {v.x, v.y, v.z, v.w};
  half4 h0;
#pragma unroll
  for (int e = 0; e < 4; ++e)
    h0[e] = (fabsf(vv[e]) < F16_MINN) ? (_Float16)0.f : (_Float16)vv[e];
  *(half4*)(o0 + (size_t)i * 4) = h0;
  float s = fmaf(v.x, v.x, fmaf(v.y, v.y, fmaf(v.z, v.z, v.w * v.w)));
#pragma unroll
  for (int off = 32; off > 0; off >>= 1) s += __shfl_down(s, off, 64);
  if (lane == 0) { c_sq[i >> 6] = s; red[w] = s; }
  __syncthreads();
  if (threadIdx.x == 0) {
    float m = fmaxf(fmaxf(red[0], red[1]), fmaxf(red[2], red[3]));
    atomicMax(&ctl[32], __float_as_uint(m));   // ctl pre-zeroed by memset
  }
}

// ---------------- x split ----------------
__global__ __launch_bounds__(256) void splitx_kernel(const float* __restrict__ in,
                                                     _Float16* __restrict__ o0, int n4) {
  int i = blockIdx.x * 256 + threadIdx.x;
  if (i >= n4) return;
  float4 v = ((const float4*)in)[i];
  float vv[4] = {v.x, v.y, v.z, v.w};
  half4 h0;
#pragma unroll
  for (int e = 0; e < 4; ++e)
    h0[e] = (fabsf(vv[e]) < F16_MINN) ? (_Float16)0.f : (_Float16)vv[e];
  *(half4*)(o0 + (size_t)i * 4) = h0;
}

// ---------------- scan: 16x16x32 f16 MFMA, 512-thr block, 2 blocks/CU, fused pm ----
// Wave w (0..7) owns c-slice chalf*256 + w*32 of each 512-c ct slice.
// A (centroids): lane l -> row l&15, k = (l>>4)*8 + e  (+kt*32)
// B (queries):   lane l -> col l&15, same k mapping
// C/D: col = lane&15 (query), row = (lane>>4)*4 + r  (centroid, within 16-tile).
// kc = blockIdx.x (fast): linear%8 = kc = XCD id -> each XCD owns ONE 4MB c0 strip.
// pmred[w][q]: per-wave running min over its 16 ct groups -> pm[kc*2+chalf][q].
__global__ __launch_bounds__(512, 4) void scan_kernel(
    const _Float16* __restrict__ x0, const _Float16* __restrict__ c0,
    const float* __restrict__ c_sq, float* __restrict__ dm,
    float* __restrict__ pm) {
  __shared__ __align__(16) _Float16 As0[32768];   // 64 KiB: [s=kt*4+quad][q(128)][8]
  __shared__ float pmred[1024];                   // 4 KiB: [w(8)][q(128)]

  const int kc = blockIdx.x;                      // kc fast -> XCD-aligned strips
  const int qb = (int)blockIdx.y >> 1, chalf = (int)blockIdx.y & 1;
  const int tid = (int)threadIdx.x;
  const int lane = tid & 63, w = tid >> 6;        // w = 0..7
  const int col = lane & 15, quad = lane >> 4;
  const int qrow0 = qb * QTILE;

  pmred[tid] = INFINITY;
  pmred[tid + 512] = INFINITY;

  // stage x tile: 4096 16B chunks; chunk u = s*128+q holds x0[qrow0+q][s*8 .. s*8+7]
#pragma unroll
  for (int i = 0; i < 8; ++i) {
    int u = i * 512 + tid;
    int q = u & 127, s = u >> 7;
    gl_lds16(x0 + (size_t)(qrow0 + q) * DDIM + s * 8, As0 + (size_t)u * 8);
  }
  __syncthreads();   // As0 + pmred ready

  for (int ct = 0; ct < STSZ / 512; ++ct) {
    const int cbase = kc * STSZ + ct * 512 + chalf * 256 + w * 32;  // 32-c group
    f32x4 acc[2][8];                                    // [cm][qn]
#pragma unroll
    for (int cm = 0; cm < 2; ++cm)
#pragma unroll
      for (int qn = 0; qn < 8; ++qn) acc[cm][qn] = (f32x4)0.0f;

#pragma unroll 2
    for (int kt = 0; kt < 8; ++kt) {
      const int k0 = kt * 32;
      half8 cf[2];
#pragma unroll
      for (int cm = 0; cm < 2; ++cm)
        cf[cm] = *(const half8*)(c0 + (size_t)(cbase + cm * 16 + col) * DDIM + k0 + quad * 8);
#pragma unroll
      for (int qn = 0; qn < 8; ++qn) {
        half8 qf = *(const half8*)(As0 + (size_t)(((kt * 4 + quad) * QTILE) + qn * 16 + col) * 8);
#pragma unroll
        for (int cm = 0; cm < 2; ++cm)
          acc[cm][qn] = __builtin_amdgcn_mfma_f32_16x16x32_f16(cf[cm], qf, acc[cm][qn], 0, 0, 0);
      }
    }

    // epilogue: d = cs - 2*dot; min over 32 centroids (2 cm x 4 rg in-lane + quad xor)
    f32x4 csv[2];
#pragma unroll
    for (int cm = 0; cm < 2; ++cm)
      csv[cm] = *(const f32x4*)(c_sq + cbase + cm * 16 + quad * 4);
    const int grp = kc * (STSZ / 32) + ct * 16 + chalf * 8 + w;
    float* dmg = dm + (size_t)grp * 4096 + qrow0;
#pragma unroll
    for (int qn = 0; qn < 8; ++qn) {
      float mq = INFINITY;
#pragma unroll
      for (int cm = 0; cm < 2; ++cm)
#pragma unroll
        for (int rg = 0; rg < 4; ++rg)
          mq = fminf(mq, fmaf(-2.0f, acc[cm][qn][rg], csv[cm][rg]));
      mq = fminf(mq, __shfl_xor(mq, 16, 64));
      mq = fminf(mq, __shfl_xor(mq, 32, 64));
      if (quad == 0) {
        dmg[qn * 16 + col] = mq;                      // 16 lanes, 64 B dense
        const int pi = w * 128 + qn * 16 + col;       // banks: col -> 16 distinct
        pmred[pi] = fminf(pmred[pi], mq);
      }
    }
  }

  __syncthreads();
  if (tid < 128) {       // column-min over 8 wave rows -> pm[kc*2+chalf][q]
    float m = INFINITY;
#pragma unroll
    for (int i = 0; i < 8; ++i) m = fminf(m, pmred[i * 128 + tid]);
    pm[(size_t)(kc * 2 + chalf) * 4096 + qrow0 + tid] = m;
  }
}

// ---------------- finish: fused tq + emit + rescore + writeback ----------------
// Block = 16 queries (grid 256, 512 thr = 8 waves).
__global__ __launch_bounds__(512) void finish_kernel(
    const float* __restrict__ pm, const float* __restrict__ x,
    const unsigned* __restrict__ ctl, const float* __restrict__ dm,
    const float* __restrict__ cent, const float* __restrict__ c_sq,
    float* __restrict__ out) {
  __shared__ float Tl[16];
  __shared__ unsigned cnt16[16];
  __shared__ unsigned short candL[16][QCAP];
  __shared__ float xred[16][33];
  __shared__ unsigned long long bestL[16];

  const int t = (int)threadIdx.x;
  const int w = t >> 6, lane = t & 63;
  const int q0 = (int)blockIdx.x * 16;

  // ph1a: xsq partials (32 threads per query, 8 floats each)
  {
    int qi = t >> 5, ch = t & 31;
    const float4* xr = (const float4*)(x + (size_t)(q0 + qi) * DDIM + ch * 8);
    float s = 0.f;
#pragma unroll
    for (int j = 0; j < 2; ++j) {
      float4 v = xr[j];
      s = fmaf(v.x, v.x, fmaf(v.y, v.y, fmaf(v.z, v.z, fmaf(v.w, v.w, s))));
    }
    xred[qi][ch] = s;
    if (t < 16) cnt16[t] = 0u;
  }
  __syncthreads();
  // ph1b: T
  if (t < 16) {
    float xsq = 0.f;
#pragma unroll
    for (int i = 0; i < 32; ++i) xsq += xred[t][i];
    float M = INFINITY;
#pragma unroll
    for (int i = 0; i < 16; ++i) M = fminf(M, pm[i * 4096 + q0 + t]);
    float cmaxsq = __uint_as_float(ctl[32]);
    // rigorous 1-term f16 bound ~2^-9 ||x|| ||c||max; margin = 4x bound + 1.0 slack
    Tl[t] = M + 0.0078125f * sqrtf(xsq * cmaxsq) + 1.0f;
  }
  __syncthreads();

  // ph2: emit (coalesced 64B dm segments; order-invariant min-over-set)
  {
    const int qi = t & 15, g0 = t >> 4;
    const float Tq = Tl[qi];
#pragma unroll 4
    for (int i = 0; i < 64; ++i) {
      int g = g0 + i * 32;
      float v = dm[(size_t)g * 4096 + q0 + qi];
      if (v <= Tq) {
        unsigned slot = atomicAdd(&cnt16[qi], 1u);
        if (slot < QCAP) candL[qi][slot] = (unsigned short)g;
      }
    }
  }
  __syncthreads();

  // ph3: rescore -- wave w handles queries w and w+8
#pragma unroll
  for (int k = 0; k < 2; ++k) {
    const int qi = w + k * 8;
    const unsigned n = cnt16[qi];
    unsigned long long bq = 0xFFFFFFFFFFFFFFFFull;
    if (n >= 1 && n <= QCAP) {
      int dh = (lane & 1) * 128;
      const float4* xr = (const float4*)(x + (size_t)(q0 + qi) * DDIM + dh);
      for (unsigned sl = 0; sl < n; ++sl) {
        int g = (int)candL[qi][sl];
        int c = g * 32 + (lane >> 1);
        const float4* cr = (const float4*)(cent + (size_t)c * DDIM + dh);
        float s = 0.f;
#pragma unroll
        for (int i = 0; i < 32; ++i) {
          float4 a = xr[i], bb = cr[i];
          s = fmaf(a.x, bb.x, fmaf(a.y, bb.y, fmaf(a.z, bb.z, fmaf(a.w, bb.w, s))));
        }
        s += __shfl_xor(s, 1, 64);
        float d = (lane & 1) ? INFINITY : fmaf(-2.0f, s, c_sq[c]);
        unsigned long long pkv = ((unsigned long long)fkey(d) << 32) | (unsigned)c;
        if (pkv < bq) bq = pkv;
      }
    } else {
      // safety net: exact argmin over all 65536 (overflow; should never trigger)
      const float4* xr = (const float4*)(x + (size_t)(q0 + qi) * DDIM);
      for (int c = lane; c < 65536; c += 64) {
        const float4* cr = (const float4*)(cent + (size_t)c * DDIM);
        float s = 0.f;
#pragma unroll 16
        for (int i = 0; i < 64; ++i) {
          float4 a = xr[i], bb = cr[i];
          s = fmaf(a.x, bb.x, fmaf(a.y, bb.y, fmaf(a.z, bb.z, fmaf(a.w, bb.w, s))));
        }
        float d = fmaf(-2.0f, s, c_sq[c]);
        unsigned long long pkv = ((unsigned long long)fkey(d) << 32) | (unsigned)c;
        if (pkv < bq) bq = pkv;
      }
    }
#pragma unroll
    for (int off = 1; off < 64; off <<= 1) {
      unsigned long long o = __shfl_xor(bq, off, 64);
      if (o < bq) bq = o;
    }
    if (lane == 0) bestL[qi] = bq;
  }
  __syncthreads();

  // writeback: 32 threads per query (2 float4 each = 256 dims), + code scalar
  {
    int qi = t >> 5, part = t & 31;
    int idx = (int)(unsigned)(bestL[qi] & 0xFFFFFFFFu);
    const float4* cr = (const float4*)(cent + (size_t)idx * DDIM);
    float4* orow = (float4*)(out + (size_t)(q0 + qi) * DDIM);
#pragma unroll
    for (int j = 0; j < 2; ++j) orow[part * 2 + j] = cr[part * 2 + j];
    if (part == 0) out[(size_t)4096 * DDIM + q0 + qi] = (float)idx;
  }
}

extern "C" void kernel_launch(void* const* d_in, const int* in_sizes, int n_in,
                              void* d_out, int out_size, void* d_ws, size_t ws_size,
                              hipStream_t stream) {
  const float* x    = (const float*)d_in[1];   // [4096,256]
  const float* cent = (const float*)d_in[2];   // [65536,256]
  float* out = (float*)d_out;
  char* ws = (char*)d_ws;

  const size_t OFF_C0   = 0;           // 33,554,432  f16 hi(centroids)
  const size_t OFF_X0   = 33554432;    //  2,097,152  f16 hi(x)
  const size_t OFF_CSQ  = 35651584;    //    262,144
  const size_t OFF_CTL  = 35913728;    //        256
  const size_t OFF_DM   = 35913984;    // 33,554,432  f32[2048][4096]
  const size_t OFF_PM   = 69468416;    //    262,144  f32[16][4096]
  const size_t NEED     = 72089600;    // proven available since round 2
  if (ws_size < NEED) return;

  _Float16* c0 = (_Float16*)(ws + OFF_C0);
  _Float16* x0 = (_Float16*)(ws + OFF_X0);
  float* c_sq = (float*)(ws + OFF_CSQ);
  unsigned* ctl = (unsigned*)(ws + OFF_CTL);
  float* dm = (float*)(ws + OFF_DM);
  float* pm = (float*)(ws + OFF_PM);

  hipMemsetAsync(ctl, 0, 256, stream);
  splitc_kernel<<<16384, 256, 0, stream>>>(cent, c0, c_sq, ctl);
  splitx_kernel<<<1024, 256, 0, stream>>>(x, x0, 4096 * 256 / 4);
  scan_kernel<<<dim3(8, 64), 512, 0, stream>>>(x0, c0, c_sq, dm, pm);
  finish_kernel<<<256, 512, 0, stream>>>(pm, x, ctl, dm, cent, c_sq, out);
}

// Round 15
// 327.946 us; speedup vs baseline: 1.5187x; 1.5187x over previous
//
#include <hip/hip_runtime.h>
#include <hip/hip_bf16.h>
#include <math.h>

// B=4096 queries, D=256, K=65536 centroids (f32).
// Round 15 (this session): surgical revert of r13's cmax-fusion. r14 counters:
// splitc 19->191us -- 16384 blocks each atomicMax'ing ONE dword = serialized
// device atomics (~28cyc each = 458K cyc = 191us, matches). Revert to unfused
// splitc + separate 64-block cmax (64 atomics, ~1us). Keep memset for ctl.
// KEEP the still-untested block-TLP scan (512-thr, grid (8,64), 2 blocks/CU)
// and finish. Arithmetic from r14 also revealed finish ~= 140us (total 498 -
// splitc 191 - scan<191 - small) -> finish is round-16's target once scan's
// number is clean. Predict: splitc ~19, cmax ~1; scan = 125 (TLP win, total
// ~300) or 158 (plateau, total ~330).

#define DDIM 256
#define QTILE 128
#define STSZ 8192      // centroids per kc strip (16 ct x 512c; block covers 256c/ct)
#define QCAP 48        // candidate groups per query
#define F16_MINN 6.103515625e-5f

typedef __attribute__((ext_vector_type(8))) _Float16 half8;
typedef __attribute__((ext_vector_type(4))) _Float16 half4;
typedef __attribute__((ext_vector_type(4))) float f32x4;

__device__ __forceinline__ void gl_lds16(const void* g, void* l) {
  __builtin_amdgcn_global_load_lds((const __attribute__((address_space(1))) void*)g,
                                   (__attribute__((address_space(3))) void*)l, 16, 0, 0);
}

// exact order-preserving float -> uint key (finite floats; matches f32 <)
__device__ __forceinline__ unsigned fkey(float d) {
  unsigned ud = __float_as_uint(d);
  return ud ^ (((int)ud < 0) ? 0xFFFFFFFFu : 0x80000000u);
}

// ---------------- centroid split + c_sq fused (one wave = one 256-elem row) --------
__global__ __launch_bounds__(256) void splitc_kernel(const float* __restrict__ in,
                                                     _Float16* __restrict__ o0,
                                                     float* __restrict__ c_sq) {
  int i = blockIdx.x * 256 + threadIdx.x;   // 4-elem chunk id; wave = one row
  int lane = (int)threadIdx.x & 63;
  float4 v = ((const float4*)in)[i];
  float vv[4] = {v.x, v.y, v.z, v.w};
  half4 h0;
#pragma unroll
  for (int e = 0; e < 4; ++e)
    h0[e] = (fabsf(vv[e]) < F16_MINN) ? (_Float16)0.f : (_Float16)vv[e];
  *(half4*)(o0 + (size_t)i * 4) = h0;
  float s = fmaf(v.x, v.x, fmaf(v.y, v.y, fmaf(v.z, v.z, v.w * v.w)));
#pragma unroll
  for (int off = 32; off > 0; off >>= 1) s += __shfl_down(s, off, 64);
  if (lane == 0) c_sq[i >> 6] = s;
}

// ---------------- x split ----------------
__global__ __launch_bounds__(256) void splitx_kernel(const float* __restrict__ in,
                                                     _Float16* __restrict__ o0, int n4) {
  int i = blockIdx.x * 256 + threadIdx.x;
  if (i >= n4) return;
  float4 v = ((const float4*)in)[i];
  float vv[4] = {v.x, v.y, v.z, v.w};
  half4 h0;
#pragma unroll
  for (int e = 0; e < 4; ++e)
    h0[e] = (fabsf(vv[e]) < F16_MINN) ? (_Float16)0.f : (_Float16)vv[e];
  *(half4*)(o0 + (size_t)i * 4) = h0;
}

// ---------------- cmax: 2-stage max of c_sq, one atomic per block (64 total) --------
__global__ __launch_bounds__(256) void cmax_kernel(const float* __restrict__ c_sq,
                                                   unsigned* __restrict__ ctl) {
  __shared__ float red[4];
  int t = blockIdx.x * 256 + (int)threadIdx.x;
  float4 v = ((const float4*)c_sq)[t];
  float m = fmaxf(fmaxf(v.x, v.y), fmaxf(v.z, v.w));
#pragma unroll
  for (int off = 32; off > 0; off >>= 1) m = fmaxf(m, __shfl_down(m, off, 64));
  int lane = (int)threadIdx.x & 63, w = (int)threadIdx.x >> 6;
  if (lane == 0) red[w] = m;
  __syncthreads();
  if (threadIdx.x == 0) {
    m = fmaxf(fmaxf(red[0], red[1]), fmaxf(red[2], red[3]));
    atomicMax(&ctl[32], __float_as_uint(m));   // ctl pre-zeroed by memset
  }
}

// ---------------- scan: 16x16x32 f16 MFMA, 512-thr block, 2 blocks/CU, fused pm ----
// Wave w (0..7) owns c-slice chalf*256 + w*32 of each 512-c ct slice.
// A (centroids): lane l -> row l&15, k = (l>>4)*8 + e  (+kt*32)
// B (queries):   lane l -> col l&15, same k mapping
// C/D: col = lane&15 (query), row = (lane>>4)*4 + r  (centroid, within 16-tile).
// kc = blockIdx.x (fast): linear%8 = kc = XCD id -> each XCD owns ONE 4MB c0 strip.
// pmred[w][q]: per-wave running min over its 16 ct groups -> pm[kc*2+chalf][q].
__global__ __launch_bounds__(512, 4) void scan_kernel(
    const _Float16* __restrict__ x0, const _Float16* __restrict__ c0,
    const float* __restrict__ c_sq, float* __restrict__ dm,
    float* __restrict__ pm) {
  __shared__ __align__(16) _Float16 As0[32768];   // 64 KiB: [s=kt*4+quad][q(128)][8]
  __shared__ float pmred[1024];                   // 4 KiB: [w(8)][q(128)]

  const int kc = blockIdx.x;                      // kc fast -> XCD-aligned strips
  const int qb = (int)blockIdx.y >> 1, chalf = (int)blockIdx.y & 1;
  const int tid = (int)threadIdx.x;
  const int lane = tid & 63, w = tid >> 6;        // w = 0..7
  const int col = lane & 15, quad = lane >> 4;
  const int qrow0 = qb * QTILE;

  pmred[tid] = INFINITY;
  pmred[tid + 512] = INFINITY;

  // stage x tile: 4096 16B chunks; chunk u = s*128+q holds x0[qrow0+q][s*8 .. s*8+7]
#pragma unroll
  for (int i = 0; i < 8; ++i) {
    int u = i * 512 + tid;
    int q = u & 127, s = u >> 7;
    gl_lds16(x0 + (size_t)(qrow0 + q) * DDIM + s * 8, As0 + (size_t)u * 8);
  }
  __syncthreads();   // As0 + pmred ready

  for (int ct = 0; ct < STSZ / 512; ++ct) {
    const int cbase = kc * STSZ + ct * 512 + chalf * 256 + w * 32;  // 32-c group
    f32x4 acc[2][8];                                    // [cm][qn]
#pragma unroll
    for (int cm = 0; cm < 2; ++cm)
#pragma unroll
      for (int qn = 0; qn < 8; ++qn) acc[cm][qn] = (f32x4)0.0f;

#pragma unroll 2
    for (int kt = 0; kt < 8; ++kt) {
      const int k0 = kt * 32;
      half8 cf[2];
#pragma unroll
      for (int cm = 0; cm < 2; ++cm)
        cf[cm] = *(const half8*)(c0 + (size_t)(cbase + cm * 16 + col) * DDIM + k0 + quad * 8);
#pragma unroll
      for (int qn = 0; qn < 8; ++qn) {
        half8 qf = *(const half8*)(As0 + (size_t)(((kt * 4 + quad) * QTILE) + qn * 16 + col) * 8);
#pragma unroll
        for (int cm = 0; cm < 2; ++cm)
          acc[cm][qn] = __builtin_amdgcn_mfma_f32_16x16x32_f16(cf[cm], qf, acc[cm][qn], 0, 0, 0);
      }
    }

    // epilogue: d = cs - 2*dot; min over 32 centroids (2 cm x 4 rg in-lane + quad xor)
    f32x4 csv[2];
#pragma unroll
    for (int cm = 0; cm < 2; ++cm)
      csv[cm] = *(const f32x4*)(c_sq + cbase + cm * 16 + quad * 4);
    const int grp = kc * (STSZ / 32) + ct * 16 + chalf * 8 + w;
    float* dmg = dm + (size_t)grp * 4096 + qrow0;
#pragma unroll
    for (int qn = 0; qn < 8; ++qn) {
      float mq = INFINITY;
#pragma unroll
      for (int cm = 0; cm < 2; ++cm)
#pragma unroll
        for (int rg = 0; rg < 4; ++rg)
          mq = fminf(mq, fmaf(-2.0f, acc[cm][qn][rg], csv[cm][rg]));
      mq = fminf(mq, __shfl_xor(mq, 16, 64));
      mq = fminf(mq, __shfl_xor(mq, 32, 64));
      if (quad == 0) {
        dmg[qn * 16 + col] = mq;                      // 16 lanes, 64 B dense
        const int pi = w * 128 + qn * 16 + col;       // banks: col -> 16 distinct
        pmred[pi] = fminf(pmred[pi], mq);
      }
    }
  }

  __syncthreads();
  if (tid < 128) {       // column-min over 8 wave rows -> pm[kc*2+chalf][q]
    float m = INFINITY;
#pragma unroll
    for (int i = 0; i < 8; ++i) m = fminf(m, pmred[i * 128 + tid]);
    pm[(size_t)(kc * 2 + chalf) * 4096 + qrow0 + tid] = m;
  }
}

// ---------------- finish: fused tq + emit + rescore + writeback ----------------
// Block = 16 queries (grid 256, 512 thr = 8 waves).
__global__ __launch_bounds__(512) void finish_kernel(
    const float* __restrict__ pm, const float* __restrict__ x,
    const unsigned* __restrict__ ctl, const float* __restrict__ dm,
    const float* __restrict__ cent, const float* __restrict__ c_sq,
    float* __restrict__ out) {
  __shared__ float Tl[16];
  __shared__ unsigned cnt16[16];
  __shared__ unsigned short candL[16][QCAP];
  __shared__ float xred[16][33];
  __shared__ unsigned long long bestL[16];

  const int t = (int)threadIdx.x;
  const int w = t >> 6, lane = t & 63;
  const int q0 = (int)blockIdx.x * 16;

  // ph1a: xsq partials (32 threads per query, 8 floats each)
  {
    int qi = t >> 5, ch = t & 31;
    const float4* xr = (const float4*)(x + (size_t)(q0 + qi) * DDIM + ch * 8);
    float s = 0.f;
#pragma unroll
    for (int j = 0; j < 2; ++j) {
      float4 v = xr[j];
      s = fmaf(v.x, v.x, fmaf(v.y, v.y, fmaf(v.z, v.z, fmaf(v.w, v.w, s))));
    }
    xred[qi][ch] = s;
    if (t < 16) cnt16[t] = 0u;
  }
  __syncthreads();
  // ph1b: T
  if (t < 16) {
    float xsq = 0.f;
#pragma unroll
    for (int i = 0; i < 32; ++i) xsq += xred[t][i];
    float M = INFINITY;
#pragma unroll
    for (int i = 0; i < 16; ++i) M = fminf(M, pm[i * 4096 + q0 + t]);
    float cmaxsq = __uint_as_float(ctl[32]);
    // rigorous 1-term f16 bound ~2^-9 ||x|| ||c||max; margin = 4x bound + 1.0 slack
    Tl[t] = M + 0.0078125f * sqrtf(xsq * cmaxsq) + 1.0f;
  }
  __syncthreads();

  // ph2: emit (coalesced 64B dm segments; order-invariant min-over-set)
  {
    const int qi = t & 15, g0 = t >> 4;
    const float Tq = Tl[qi];
#pragma unroll 4
    for (int i = 0; i < 64; ++i) {
      int g = g0 + i * 32;
      float v = dm[(size_t)g * 4096 + q0 + qi];
      if (v <= Tq) {
        unsigned slot = atomicAdd(&cnt16[qi], 1u);
        if (slot < QCAP) candL[qi][slot] = (unsigned short)g;
      }
    }
  }
  __syncthreads();

  // ph3: rescore -- wave w handles queries w and w+8
#pragma unroll
  for (int k = 0; k < 2; ++k) {
    const int qi = w + k * 8;
    const unsigned n = cnt16[qi];
    unsigned long long bq = 0xFFFFFFFFFFFFFFFFull;
    if (n >= 1 && n <= QCAP) {
      int dh = (lane & 1) * 128;
      const float4* xr = (const float4*)(x + (size_t)(q0 + qi) * DDIM + dh);
      for (unsigned sl = 0; sl < n; ++sl) {
        int g = (int)candL[qi][sl];
        int c = g * 32 + (lane >> 1);
        const float4* cr = (const float4*)(cent + (size_t)c * DDIM + dh);
        float s = 0.f;
#pragma unroll
        for (int i = 0; i < 32; ++i) {
          float4 a = xr[i], bb = cr[i];
          s = fmaf(a.x, bb.x, fmaf(a.y, bb.y, fmaf(a.z, bb.z, fmaf(a.w, bb.w, s))));
        }
        s += __shfl_xor(s, 1, 64);
        float d = (lane & 1) ? INFINITY : fmaf(-2.0f, s, c_sq[c]);
        unsigned long long pkv = ((unsigned long long)fkey(d) << 32) | (unsigned)c;
        if (pkv < bq) bq = pkv;
      }
    } else {
      // safety net: exact argmin over all 65536 (overflow; should never trigger)
      const float4* xr = (const float4*)(x + (size_t)(q0 + qi) * DDIM);
      for (int c = lane; c < 65536; c += 64) {
        const float4* cr = (const float4*)(cent + (size_t)c * DDIM);
        float s = 0.f;
#pragma unroll 16
        for (int i = 0; i < 64; ++i) {
          float4 a = xr[i], bb = cr[i];
          s = fmaf(a.x, bb.x, fmaf(a.y, bb.y, fmaf(a.z, bb.z, fmaf(a.w, bb.w, s))));
        }
        float d = fmaf(-2.0f, s, c_sq[c]);
        unsigned long long pkv = ((unsigned long long)fkey(d) << 32) | (unsigned)c;
        if (pkv < bq) bq = pkv;
      }
    }
#pragma unroll
    for (int off = 1; off < 64; off <<= 1) {
      unsigned long long o = __shfl_xor(bq, off, 64);
      if (o < bq) bq = o;
    }
    if (lane == 0) bestL[qi] = bq;
  }
  __syncthreads();

  // writeback: 32 threads per query (2 float4 each = 256 dims), + code scalar
  {
    int qi = t >> 5, part = t & 31;
    int idx = (int)(unsigned)(bestL[qi] & 0xFFFFFFFFu);
    const float4* cr = (const float4*)(cent + (size_t)idx * DDIM);
    float4* orow = (float4*)(out + (size_t)(q0 + qi) * DDIM);
#pragma unroll
    for (int j = 0; j < 2; ++j) orow[part * 2 + j] = cr[part * 2 + j];
    if (part == 0) out[(size_t)4096 * DDIM + q0 + qi] = (float)idx;
  }
}

extern "C" void kernel_launch(void* const* d_in, const int* in_sizes, int n_in,
                              void* d_out, int out_size, void* d_ws, size_t ws_size,
                              hipStream_t stream) {
  const float* x    = (const float*)d_in[1];   // [4096,256]
  const float* cent = (const float*)d_in[2];   // [65536,256]
  float* out = (float*)d_out;
  char* ws = (char*)d_ws;

  const size_t OFF_C0   = 0;           // 33,554,432  f16 hi(centroids)
  const size_t OFF_X0   = 33554432;    //  2,097,152  f16 hi(x)
  const size_t OFF_CSQ  = 35651584;    //    262,144
  const size_t OFF_CTL  = 35913728;    //        256
  const size_t OFF_DM   = 35913984;    // 33,554,432  f32[2048][4096]
  const size_t OFF_PM   = 69468416;    //    262,144  f32[16][4096]
  const size_t NEED     = 72089600;    // proven available since round 2
  if (ws_size < NEED) return;

  _Float16* c0 = (_Float16*)(ws + OFF_C0);
  _Float16* x0 = (_Float16*)(ws + OFF_X0);
  float* c_sq = (float*)(ws + OFF_CSQ);
  unsigned* ctl = (unsigned*)(ws + OFF_CTL);
  float* dm = (float*)(ws + OFF_DM);
  float* pm = (float*)(ws + OFF_PM);

  hipMemsetAsync(ctl, 0, 256, stream);
  splitc_kernel<<<16384, 256, 0, stream>>>(cent, c0, c_sq);
  splitx_kernel<<<1024, 256, 0, stream>>>(x, x0, 4096 * 256 / 4);
  cmax_kernel<<<64, 256, 0, stream>>>(c_sq, ctl);
  scan_kernel<<<dim3(8, 64), 512, 0, stream>>>(x0, c0, c_sq, dm, pm);
  finish_kernel<<<256, 512, 0, stream>>>(pm, x, ctl, dm, cent, c_sq, out);
}

// Round 16
// 327.080 us; speedup vs baseline: 1.5228x; 1.0026x over previous
//
#include <hip/hip_runtime.h>
#include <hip/hip_bf16.h>
#include <math.h>

// B=4096 queries, D=256, K=65536 centroids (f32).
// Round 16 (this session): finish restructure. r15 closed scan (block-TLP null:
// 160.5 vs 158; 7 variants all 158-169 @ 38% MfmaUtil = per-wave latency
// plateau). Bookkeeping: finish ~= 130-140us (total 327.9 - scan 160.5 -
// splits ~22 - gaps). finish was grid 256 (1 block/CU), ph3 serializing 2
// queries/wave over ~n x 32KB L3-latency candidate reads. Restructure: 512
// blocks x 512 thr, 8 q/block, 1 query PER WAVE (k-loop gone), 2 blocks/CU ->
// 2x ph3 wave-parallelism + finer block granularity (per-block time = max over
// 8 not 16 queries). ph1 = wave-per-query shfl reduce (xred LDS deleted); ph2
// qi=t&7,g0=t>>3 (32B dm segments, L3-absorbed); writeback = 1 float4/lane.
// Same thresholds/tie-breaks/fallback. Predict: finish ~70-90, total 270-295;
// if >=320 -> finish is emit/BW-bound not latency -> phase-split probe next.

#define DDIM 256
#define QTILE 128
#define STSZ 8192      // centroids per kc strip (16 ct x 512c; block covers 256c/ct)
#define QCAP 48        // candidate groups per query
#define F16_MINN 6.103515625e-5f

typedef __attribute__((ext_vector_type(8))) _Float16 half8;
typedef __attribute__((ext_vector_type(4))) _Float16 half4;
typedef __attribute__((ext_vector_type(4))) float f32x4;

__device__ __forceinline__ void gl_lds16(const void* g, void* l) {
  __builtin_amdgcn_global_load_lds((const __attribute__((address_space(1))) void*)g,
                                   (__attribute__((address_space(3))) void*)l, 16, 0, 0);
}

// exact order-preserving float -> uint key (finite floats; matches f32 <)
__device__ __forceinline__ unsigned fkey(float d) {
  unsigned ud = __float_as_uint(d);
  return ud ^ (((int)ud < 0) ? 0xFFFFFFFFu : 0x80000000u);
}

// ---------------- centroid split + c_sq fused (one wave = one 256-elem row) --------
__global__ __launch_bounds__(256) void splitc_kernel(const float* __restrict__ in,
                                                     _Float16* __restrict__ o0,
                                                     float* __restrict__ c_sq) {
  int i = blockIdx.x * 256 + threadIdx.x;   // 4-elem chunk id; wave = one row
  int lane = (int)threadIdx.x & 63;
  float4 v = ((const float4*)in)[i];
  float vv[4] = {v.x, v.y, v.z, v.w};
  half4 h0;
#pragma unroll
  for (int e = 0; e < 4; ++e)
    h0[e] = (fabsf(vv[e]) < F16_MINN) ? (_Float16)0.f : (_Float16)vv[e];
  *(half4*)(o0 + (size_t)i * 4) = h0;
  float s = fmaf(v.x, v.x, fmaf(v.y, v.y, fmaf(v.z, v.z, v.w * v.w)));
#pragma unroll
  for (int off = 32; off > 0; off >>= 1) s += __shfl_down(s, off, 64);
  if (lane == 0) c_sq[i >> 6] = s;
}

// ---------------- x split ----------------
__global__ __launch_bounds__(256) void splitx_kernel(const float* __restrict__ in,
                                                     _Float16* __restrict__ o0, int n4) {
  int i = blockIdx.x * 256 + threadIdx.x;
  if (i >= n4) return;
  float4 v = ((const float4*)in)[i];
  float vv[4] = {v.x, v.y, v.z, v.w};
  half4 h0;
#pragma unroll
  for (int e = 0; e < 4; ++e)
    h0[e] = (fabsf(vv[e]) < F16_MINN) ? (_Float16)0.f : (_Float16)vv[e];
  *(half4*)(o0 + (size_t)i * 4) = h0;
}

// ---------------- cmax: 2-stage max of c_sq, one atomic per block (64 total) --------
__global__ __launch_bounds__(256) void cmax_kernel(const float* __restrict__ c_sq,
                                                   unsigned* __restrict__ ctl) {
  __shared__ float red[4];
  int t = blockIdx.x * 256 + (int)threadIdx.x;
  float4 v = ((const float4*)c_sq)[t];
  float m = fmaxf(fmaxf(v.x, v.y), fmaxf(v.z, v.w));
#pragma unroll
  for (int off = 32; off > 0; off >>= 1) m = fmaxf(m, __shfl_down(m, off, 64));
  int lane = (int)threadIdx.x & 63, w = (int)threadIdx.x >> 6;
  if (lane == 0) red[w] = m;
  __syncthreads();
  if (threadIdx.x == 0) {
    m = fmaxf(fmaxf(red[0], red[1]), fmaxf(red[2], red[3]));
    atomicMax(&ctl[32], __float_as_uint(m));   // ctl pre-zeroed by memset
  }
}

// ---------------- scan: 16x16x32 f16 MFMA, 512-thr block, 2 blocks/CU, fused pm ----
// Wave w (0..7) owns c-slice chalf*256 + w*32 of each 512-c ct slice.
// A (centroids): lane l -> row l&15, k = (l>>4)*8 + e  (+kt*32)
// B (queries):   lane l -> col l&15, same k mapping
// C/D: col = lane&15 (query), row = (lane>>4)*4 + r  (centroid, within 16-tile).
// kc = blockIdx.x (fast): linear%8 = kc = XCD id -> each XCD owns ONE 4MB c0 strip.
// pmred[w][q]: per-wave running min over its 16 ct groups -> pm[kc*2+chalf][q].
__global__ __launch_bounds__(512, 4) void scan_kernel(
    const _Float16* __restrict__ x0, const _Float16* __restrict__ c0,
    const float* __restrict__ c_sq, float* __restrict__ dm,
    float* __restrict__ pm) {
  __shared__ __align__(16) _Float16 As0[32768];   // 64 KiB: [s=kt*4+quad][q(128)][8]
  __shared__ float pmred[1024];                   // 4 KiB: [w(8)][q(128)]

  const int kc = blockIdx.x;                      // kc fast -> XCD-aligned strips
  const int qb = (int)blockIdx.y >> 1, chalf = (int)blockIdx.y & 1;
  const int tid = (int)threadIdx.x;
  const int lane = tid & 63, w = tid >> 6;        // w = 0..7
  const int col = lane & 15, quad = lane >> 4;
  const int qrow0 = qb * QTILE;

  pmred[tid] = INFINITY;
  pmred[tid + 512] = INFINITY;

  // stage x tile: 4096 16B chunks; chunk u = s*128+q holds x0[qrow0+q][s*8 .. s*8+7]
#pragma unroll
  for (int i = 0; i < 8; ++i) {
    int u = i * 512 + tid;
    int q = u & 127, s = u >> 7;
    gl_lds16(x0 + (size_t)(qrow0 + q) * DDIM + s * 8, As0 + (size_t)u * 8);
  }
  __syncthreads();   // As0 + pmred ready

  for (int ct = 0; ct < STSZ / 512; ++ct) {
    const int cbase = kc * STSZ + ct * 512 + chalf * 256 + w * 32;  // 32-c group
    f32x4 acc[2][8];                                    // [cm][qn]
#pragma unroll
    for (int cm = 0; cm < 2; ++cm)
#pragma unroll
      for (int qn = 0; qn < 8; ++qn) acc[cm][qn] = (f32x4)0.0f;

#pragma unroll 2
    for (int kt = 0; kt < 8; ++kt) {
      const int k0 = kt * 32;
      half8 cf[2];
#pragma unroll
      for (int cm = 0; cm < 2; ++cm)
        cf[cm] = *(const half8*)(c0 + (size_t)(cbase + cm * 16 + col) * DDIM + k0 + quad * 8);
#pragma unroll
      for (int qn = 0; qn < 8; ++qn) {
        half8 qf = *(const half8*)(As0 + (size_t)(((kt * 4 + quad) * QTILE) + qn * 16 + col) * 8);
#pragma unroll
        for (int cm = 0; cm < 2; ++cm)
          acc[cm][qn] = __builtin_amdgcn_mfma_f32_16x16x32_f16(cf[cm], qf, acc[cm][qn], 0, 0, 0);
      }
    }

    // epilogue: d = cs - 2*dot; min over 32 centroids (2 cm x 4 rg in-lane + quad xor)
    f32x4 csv[2];
#pragma unroll
    for (int cm = 0; cm < 2; ++cm)
      csv[cm] = *(const f32x4*)(c_sq + cbase + cm * 16 + quad * 4);
    const int grp = kc * (STSZ / 32) + ct * 16 + chalf * 8 + w;
    float* dmg = dm + (size_t)grp * 4096 + qrow0;
#pragma unroll
    for (int qn = 0; qn < 8; ++qn) {
      float mq = INFINITY;
#pragma unroll
      for (int cm = 0; cm < 2; ++cm)
#pragma unroll
        for (int rg = 0; rg < 4; ++rg)
          mq = fminf(mq, fmaf(-2.0f, acc[cm][qn][rg], csv[cm][rg]));
      mq = fminf(mq, __shfl_xor(mq, 16, 64));
      mq = fminf(mq, __shfl_xor(mq, 32, 64));
      if (quad == 0) {
        dmg[qn * 16 + col] = mq;                      // 16 lanes, 64 B dense
        const int pi = w * 128 + qn * 16 + col;       // banks: col -> 16 distinct
        pmred[pi] = fminf(pmred[pi], mq);
      }
    }
  }

  __syncthreads();
  if (tid < 128) {       // column-min over 8 wave rows -> pm[kc*2+chalf][q]
    float m = INFINITY;
#pragma unroll
    for (int i = 0; i < 8; ++i) m = fminf(m, pmred[i * 128 + tid]);
    pm[(size_t)(kc * 2 + chalf) * 4096 + qrow0 + tid] = m;
  }
}

// ---------------- finish: fused tq + emit + rescore + writeback ----------------
// Block = 8 queries (grid 512, 512 thr = 8 waves, 1 query per wave).
__global__ __launch_bounds__(512) void finish_kernel(
    const float* __restrict__ pm, const float* __restrict__ x,
    const unsigned* __restrict__ ctl, const float* __restrict__ dm,
    const float* __restrict__ cent, const float* __restrict__ c_sq,
    float* __restrict__ out) {
  __shared__ float Tl[8];
  __shared__ unsigned cnt8[8];
  __shared__ unsigned short candL[8][QCAP];
  __shared__ unsigned long long bestL[8];

  const int t = (int)threadIdx.x;
  const int w = t >> 6, lane = t & 63;
  const int q0 = (int)blockIdx.x * 8;

  // ph1: wave w computes xsq for query q0+w (one float4/lane), then T
  {
    float4 v = ((const float4*)(x + (size_t)(q0 + w) * DDIM))[lane];
    float s = fmaf(v.x, v.x, fmaf(v.y, v.y, fmaf(v.z, v.z, v.w * v.w)));
#pragma unroll
    for (int off = 32; off > 0; off >>= 1) s += __shfl_down(s, off, 64);
    if (lane == 0) {
      float M = INFINITY;
#pragma unroll
      for (int i = 0; i < 16; ++i) M = fminf(M, pm[i * 4096 + q0 + w]);
      float cmaxsq = __uint_as_float(ctl[32]);
      // rigorous 1-term f16 bound ~2^-9 ||x|| ||c||max; margin = 4x bound + 1.0 slack
      Tl[w] = M + 0.0078125f * sqrtf(s * cmaxsq) + 1.0f;
      cnt8[w] = 0u;
    }
  }
  __syncthreads();

  // ph2: emit (qi = t&7, g0 = t>>3; 32B dm segments; order-invariant min-over-set)
  {
    const int qi = t & 7, g0 = t >> 3;
    const float Tq = Tl[qi];
#pragma unroll 4
    for (int i = 0; i < 32; ++i) {
      int g = g0 + i * 64;
      float v = dm[(size_t)g * 4096 + q0 + qi];
      if (v <= Tq) {
        unsigned slot = atomicAdd(&cnt8[qi], 1u);
        if (slot < QCAP) candL[qi][slot] = (unsigned short)g;
      }
    }
  }
  __syncthreads();

  // ph3: wave w rescores query q0+w (1:1, no serialization)
  {
    const unsigned n = cnt8[w];
    unsigned long long bq = 0xFFFFFFFFFFFFFFFFull;
    if (n >= 1 && n <= QCAP) {
      int dh = (lane & 1) * 128;
      const float4* xr = (const float4*)(x + (size_t)(q0 + w) * DDIM + dh);
      for (unsigned sl = 0; sl < n; ++sl) {
        int g = (int)candL[w][sl];
        int c = g * 32 + (lane >> 1);
        const float4* cr = (const float4*)(cent + (size_t)c * DDIM + dh);
        float s = 0.f;
#pragma unroll
        for (int i = 0; i < 32; ++i) {
          float4 a = xr[i], bb = cr[i];
          s = fmaf(a.x, bb.x, fmaf(a.y, bb.y, fmaf(a.z, bb.z, fmaf(a.w, bb.w, s))));
        }
        s += __shfl_xor(s, 1, 64);
        float d = (lane & 1) ? INFINITY : fmaf(-2.0f, s, c_sq[c]);
        unsigned long long pkv = ((unsigned long long)fkey(d) << 32) | (unsigned)c;
        if (pkv < bq) bq = pkv;
      }
    } else {
      // safety net: exact argmin over all 65536 (overflow; should never trigger)
      const float4* xr = (const float4*)(x + (size_t)(q0 + w) * DDIM);
      for (int c = lane; c < 65536; c += 64) {
        const float4* cr = (const float4*)(cent + (size_t)c * DDIM);
        float s = 0.f;
#pragma unroll 16
        for (int i = 0; i < 64; ++i) {
          float4 a = xr[i], bb = cr[i];
          s = fmaf(a.x, bb.x, fmaf(a.y, bb.y, fmaf(a.z, bb.z, fmaf(a.w, bb.w, s))));
        }
        float d = fmaf(-2.0f, s, c_sq[c]);
        unsigned long long pkv = ((unsigned long long)fkey(d) << 32) | (unsigned)c;
        if (pkv < bq) bq = pkv;
      }
    }
#pragma unroll
    for (int off = 1; off < 64; off <<= 1) {
      unsigned long long o = __shfl_xor(bq, off, 64);
      if (o < bq) bq = o;
    }
    if (lane == 0) bestL[w] = bq;
  }
  __syncthreads();

  // writeback: wave w writes query q0+w's row (one float4 per lane) + code scalar
  {
    int idx = (int)(unsigned)(bestL[w] & 0xFFFFFFFFu);
    float4 v = ((const float4*)(cent + (size_t)idx * DDIM))[lane];
    ((float4*)(out + (size_t)(q0 + w) * DDIM))[lane] = v;
    if (lane == 0) out[(size_t)4096 * DDIM + q0 + w] = (float)idx;
  }
}

extern "C" void kernel_launch(void* const* d_in, const int* in_sizes, int n_in,
                              void* d_out, int out_size, void* d_ws, size_t ws_size,
                              hipStream_t stream) {
  const float* x    = (const float*)d_in[1];   // [4096,256]
  const float* cent = (const float*)d_in[2];   // [65536,256]
  float* out = (float*)d_out;
  char* ws = (char*)d_ws;

  const size_t OFF_C0   = 0;           // 33,554,432  f16 hi(centroids)
  const size_t OFF_X0   = 33554432;    //  2,097,152  f16 hi(x)
  const size_t OFF_CSQ  = 35651584;    //    262,144
  const size_t OFF_CTL  = 35913728;    //        256
  const size_t OFF_DM   = 35913984;    // 33,554,432  f32[2048][4096]
  const size_t OFF_PM   = 69468416;    //    262,144  f32[16][4096]
  const size_t NEED     = 72089600;    // proven available since round 2
  if (ws_size < NEED) return;

  _Float16* c0 = (_Float16*)(ws + OFF_C0);
  _Float16* x0 = (_Float16*)(ws + OFF_X0);
  float* c_sq = (float*)(ws + OFF_CSQ);
  unsigned* ctl = (unsigned*)(ws + OFF_CTL);
  float* dm = (float*)(ws + OFF_DM);
  float* pm = (float*)(ws + OFF_PM);

  hipMemsetAsync(ctl, 0, 256, stream);
  splitc_kernel<<<16384, 256, 0, stream>>>(cent, c0, c_sq);
  splitx_kernel<<<1024, 256, 0, stream>>>(x, x0, 4096 * 256 / 4);
  cmax_kernel<<<64, 256, 0, stream>>>(c_sq, ctl);
  scan_kernel<<<dim3(8, 64), 512, 0, stream>>>(x0, c0, c_sq, dm, pm);
  finish_kernel<<<512, 512, 0, stream>>>(pm, x, ctl, dm, cent, c_sq, out);
}